// Round 1
// baseline (14363.780 us; speedup 1.0000x reference)
//
#include <hip/hip_runtime.h>
#include <hip/hip_bf16.h>

#define SEQ   2048
#define NBATCH 64
#define HID   512
#define KDIM  512

typedef float f32x4  __attribute__((ext_vector_type(4)));
typedef short bf16x8 __attribute__((ext_vector_type(8)));

__device__ __forceinline__ unsigned short f2bf(float f) {
  union { float f; unsigned int u; } v; v.f = f;
  unsigned int r = v.u + 0x7FFFu + ((v.u >> 16) & 1u);
  return (unsigned short)(r >> 16);
}

__device__ __forceinline__ f32x4 mfma16(bf16x8 a, bf16x8 b, f32x4 c) {
  return __builtin_amdgcn_mfma_f32_16x16x32_bf16(a, b, c, 0, 0, 0);
}

// Repack W [H=512 rows n][K=512 cols k] (row-major fp32) into MFMA-B-fragment-major bf16:
// element index = ((kf*32 + cfg)*64 + lane)*8 + e  with n = cfg*16 + (lane&15),
// k = kf*32 + (lane>>4)*8 + e.  (k-convention g*8+e used consistently for A and B.)
__global__ void prep_wfrag(const float* __restrict__ W, unsigned short* __restrict__ dst) {
  int tid = blockIdx.x * blockDim.x + threadIdx.x;   // 0 .. 262143
  int e   = tid & 7;
  int l   = (tid >> 3) & 63;
  int cfg = (tid >> 9) & 31;
  int kf  = tid >> 14;
  int n = cfg * 16 + (l & 15);
  int k = kf * 32 + (l >> 4) * 8 + e;
  dst[tid] = f2bf(W[n * KDIM + k]);
}

__global__ void prep_bsum(const float* __restrict__ a, const float* __restrict__ b,
                          float* __restrict__ out) {
  int j = threadIdx.x;
  if (j < HID) out[j] = a[j] + b[j];
}

// Phase 1: xp = X * W_ih^T + (b_ih + b_hh), written into d_out (reused as xp buffer).
// Block: 512 threads (8 waves as 2 row-groups x 4 col-groups), 64 rows x 512 cols per block.
__global__ __launch_bounds__(512) void rnn_xproj(
    const float* __restrict__ X,      // [131072, 512] fp32
    const uint4* __restrict__ BW,     // W_ih frag-major bf16
    const float* __restrict__ bsum,   // [512]
    float* __restrict__ out) {        // [131072, 512] fp32 (xp)
  const int tid = threadIdx.x, w = tid >> 6, l = tid & 63;
  const int g = l >> 4, lr = l & 15;
  const int rowbase = blockIdx.x * 64 + (w >> 2) * 32;
  const int colw = (w & 3) * 128;

  f32x4 acc[2][8];
  #pragma unroll
  for (int cf = 0; cf < 8; ++cf) {
    float bv = bsum[colw + cf * 16 + lr];
    f32x4 z = {bv, bv, bv, bv};
    acc[0][cf] = z; acc[1][cf] = z;
  }

  #pragma unroll 1
  for (int kc = 0; kc < 16; ++kc) {
    const int kb = kc * 32 + g * 8;
    bf16x8 afr[2];
    #pragma unroll
    for (int ai = 0; ai < 2; ++ai) {
      const float* src = X + (size_t)(rowbase + ai * 16 + lr) * KDIM + kb;
      float4 lo = *reinterpret_cast<const float4*>(src);
      float4 hi = *reinterpret_cast<const float4*>(src + 4);
      bf16x8 a;
      a[0] = (short)f2bf(lo.x); a[1] = (short)f2bf(lo.y);
      a[2] = (short)f2bf(lo.z); a[3] = (short)f2bf(lo.w);
      a[4] = (short)f2bf(hi.x); a[5] = (short)f2bf(hi.y);
      a[6] = (short)f2bf(hi.z); a[7] = (short)f2bf(hi.w);
      afr[ai] = a;
    }
    #pragma unroll
    for (int cf = 0; cf < 8; ++cf) {
      const int cfg = (w & 3) * 8 + cf;
      uint4 braw = BW[(kc * 32 + cfg) * 64 + l];
      bf16x8 b = __builtin_bit_cast(bf16x8, braw);
      acc[0][cf] = mfma16(afr[0], b, acc[0][cf]);
      acc[1][cf] = mfma16(afr[1], b, acc[1][cf]);
    }
  }

  // C/D layout: col = lane&15, row = (lane>>4)*4 + reg  (HW-verified)
  #pragma unroll
  for (int ai = 0; ai < 2; ++ai) {
    #pragma unroll
    for (int cf = 0; cf < 8; ++cf) {
      const int col = colw + cf * 16 + lr;
      #pragma unroll
      for (int r = 0; r < 4; ++r) {
        const int row = rowbase + ai * 16 + g * 4 + r;
        out[(size_t)row * HID + col] = acc[ai][cf][r];
      }
    }
  }
}

// Phase 2: sequential scan. 4 blocks, each owns 16 batch rows for all 2048 steps.
// W_hh resident: k<128 in LDS (128 KB), k>=128 in VGPR B-fragments (192 VGPR/thread).
// h (16x512 bf16) in LDS, XOR-swizzled. xp read from d_out, overwritten with h.
__global__ __launch_bounds__(512, 2) void rnn_scan(
    const uint4* __restrict__ BW,   // W_hh frag-major bf16 (16384 frags)
    float* __restrict__ xo) {       // d_out: xp in, h out
  extern __shared__ char smem[];    // [0,131072): B kf0..3 ; [131072,147456): h
  const int tid = threadIdx.x, w = tid >> 6, l = tid & 63;
  const int g = l >> 4, lr = l & 15;
  const int bg = blockIdx.x;

  // stage LDS B-frags (kf 0..3): first 131072 bytes of BW
  {
    uint4* lb = reinterpret_cast<uint4*>(smem);
    for (int i = tid; i < 8192; i += 512) lb[i] = BW[i];
  }
  // zero h
  {
    float* hz = reinterpret_cast<float*>(smem + 131072);
    for (int i = tid; i < 4096; i += 512) hz[i] = 0.f;
  }
  // preload register B-frags: kf 4..15, this wave's 4 col-frags
  bf16x8 breg[12][4];
  #pragma unroll
  for (int kf = 0; kf < 12; ++kf)
    #pragma unroll
    for (int cf = 0; cf < 4; ++cf)
      breg[kf][cf] = __builtin_bit_cast(bf16x8,
          BW[((kf + 4) * 32 + (w * 4 + cf)) * 64 + l]);
  __syncthreads();

  const int abase = 131072 + lr * 1024 + g * 16;  // A-frag byte addr (kf term added below)
  const int aswz  = (lr & 7) << 4;
  const int colw  = w * 64;

  #pragma unroll 1
  for (int s = 0; s < SEQ; ++s) {
    float* xrow = xo + (size_t)(s * NBATCH + bg * 16) * HID;

    // prefetch xp (consumed only after the MFMA chain -> latency hidden)
    float xpv[4][4];
    #pragma unroll
    for (int cf = 0; cf < 4; ++cf) {
      const int col = colw + cf * 16 + lr;
      #pragma unroll
      for (int r = 0; r < 4; ++r)
        xpv[cf][r] = xrow[(g * 4 + r) * HID + col];
    }

    f32x4 acc[4];
    #pragma unroll
    for (int cf = 0; cf < 4; ++cf) { f32x4 z = {0.f,0.f,0.f,0.f}; acc[cf] = z; }

    #pragma unroll
    for (int kf = 0; kf < 16; ++kf) {
      bf16x8 a = *reinterpret_cast<const bf16x8*>(smem + ((abase + kf * 64) ^ aswz));
      if (kf < 4) {
        #pragma unroll
        for (int cf = 0; cf < 4; ++cf) {
          bf16x8 b = *reinterpret_cast<const bf16x8*>(
              smem + (((kf * 32 + (w * 4 + cf)) * 64 + l) << 4));
          acc[cf] = mfma16(a, b, acc[cf]);
        }
      } else {
        #pragma unroll
        for (int cf = 0; cf < 4; ++cf)
          acc[cf] = mfma16(a, breg[kf - 4][cf], acc[cf]);
      }
    }
    __syncthreads();   // all h reads done before overwrite

    #pragma unroll
    for (int cf = 0; cf < 4; ++cf) {
      const int col = colw + cf * 16 + lr;
      #pragma unroll
      for (int r = 0; r < 4; ++r) {
        const float pre = acc[cf][r] + xpv[cf][r];
        // tanh(x) = 1 - 2/(1+e^{2x}); inf-safe, |err| ~1e-6
        const float hv = 1.0f - 2.0f * __builtin_amdgcn_rcpf(1.0f + __expf(2.0f * pre));
        xrow[(g * 4 + r) * HID + col] = hv;          // fp32 output (overwrites xp)
        const int hr = g * 4 + r;
        const int waddr = (131072 + hr * 1024 + col * 2) ^ ((hr & 7) << 4);
        *reinterpret_cast<unsigned short*>(smem + waddr) = f2bf(hv);
      }
    }
    __syncthreads();   // h ready for next step
  }
}

extern "C" void kernel_launch(void* const* d_in, const int* in_sizes, int n_in,
                              void* d_out, int out_size, void* d_ws, size_t ws_size,
                              hipStream_t stream) {
  (void)in_sizes; (void)n_in; (void)out_size;
  const float* X   = (const float*)d_in[0];
  const float* Wih = (const float*)d_in[1];
  const float* Whh = (const float*)d_in[2];
  const float* bih = (const float*)d_in[3];
  const float* bhh = (const float*)d_in[4];
  float* out = (float*)d_out;

  unsigned short* wihf = (unsigned short*)d_ws;              // 512 KB
  unsigned short* whhf = wihf + 262144;                      // 512 KB
  float* bsum = (float*)(whhf + 262144);                     // 2 KB
  if (ws_size < (size_t)(2 * 524288 + 2048)) return;

  prep_wfrag<<<1024, 256, 0, stream>>>(Wih, wihf);
  prep_wfrag<<<1024, 256, 0, stream>>>(Whh, whhf);
  prep_bsum<<<1, 512, 0, stream>>>(bih, bhh, bsum);

  rnn_xproj<<<2048, 512, 0, stream>>>(X, (const uint4*)wihf, bsum, out);

  // 144 KB dynamic LDS (>64 KB needs opt-in; idempotent, graph-capture-safe)
  hipFuncSetAttribute(reinterpret_cast<const void*>(rnn_scan),
                      hipFuncAttributeMaxDynamicSharedMemorySize, 147456);
  rnn_scan<<<4, 512, 147456, stream>>>((const uint4*)whhf, out);
}

// Round 2
// 10492.693 us; speedup vs baseline: 1.3689x; 1.3689x over previous
//
#include <hip/hip_runtime.h>
#include <hip/hip_bf16.h>

#define SEQ   2048
#define NBATCH 64
#define HID   512
#define KDIM  512

typedef float f32x4  __attribute__((ext_vector_type(4)));
typedef short bf16x8 __attribute__((ext_vector_type(8)));

__device__ __forceinline__ unsigned short f2bf(float f) {
  union { float f; unsigned int u; } v; v.f = f;
  unsigned int r = v.u + 0x7FFFu + ((v.u >> 16) & 1u);
  return (unsigned short)(r >> 16);
}

__device__ __forceinline__ f32x4 mfma16(bf16x8 a, bf16x8 b, f32x4 c) {
  return __builtin_amdgcn_mfma_f32_16x16x32_bf16(a, b, c, 0, 0, 0);
}

__device__ __forceinline__ void gld_lds16(const void* gsrc, void* lds) {
  __builtin_amdgcn_global_load_lds(
      (const __attribute__((address_space(1))) unsigned int*)gsrc,
      (__attribute__((address_space(3))) unsigned int*)lds, 16, 0, 0);
}

// Repack W [H=512 rows n][K=512 cols k] (row-major fp32) into MFMA-B-fragment-major bf16:
// element index = ((kf*32 + cfg)*64 + lane)*8 + e  with n = cfg*16 + (lane&15),
// k = kf*32 + (lane>>4)*8 + e.
__global__ void prep_wfrag(const float* __restrict__ W, unsigned short* __restrict__ dst) {
  int tid = blockIdx.x * blockDim.x + threadIdx.x;   // 0 .. 262143
  int e   = tid & 7;
  int l   = (tid >> 3) & 63;
  int cfg = (tid >> 9) & 31;
  int kf  = tid >> 14;
  int n = cfg * 16 + (l & 15);
  int k = kf * 32 + (l >> 4) * 8 + e;
  dst[tid] = f2bf(W[n * KDIM + k]);
}

__global__ void prep_bsum(const float* __restrict__ a, const float* __restrict__ b,
                          float* __restrict__ out) {
  int j = threadIdx.x;
  if (j < HID) out[j] = a[j] + b[j];
}

// Phase 1: xp = X * W_ih^T + (b_ih + b_hh), written into d_out (reused as xp buffer).
__global__ __launch_bounds__(512) void rnn_xproj(
    const float* __restrict__ X,      // [131072, 512] fp32
    const uint4* __restrict__ BW,     // W_ih frag-major bf16
    const float* __restrict__ bsum,   // [512]
    float* __restrict__ out) {        // [131072, 512] fp32 (xp)
  const int tid = threadIdx.x, w = tid >> 6, l = tid & 63;
  const int g = l >> 4, lr = l & 15;
  const int rowbase = blockIdx.x * 64 + (w >> 2) * 32;
  const int colw = (w & 3) * 128;

  f32x4 acc[2][8];
  #pragma unroll
  for (int cf = 0; cf < 8; ++cf) {
    float bv = bsum[colw + cf * 16 + lr];
    f32x4 z = {bv, bv, bv, bv};
    acc[0][cf] = z; acc[1][cf] = z;
  }

  #pragma unroll 1
  for (int kc = 0; kc < 16; ++kc) {
    const int kb = kc * 32 + g * 8;
    bf16x8 afr[2];
    #pragma unroll
    for (int ai = 0; ai < 2; ++ai) {
      const float* src = X + (size_t)(rowbase + ai * 16 + lr) * KDIM + kb;
      float4 lo = *reinterpret_cast<const float4*>(src);
      float4 hi = *reinterpret_cast<const float4*>(src + 4);
      bf16x8 a;
      a[0] = (short)f2bf(lo.x); a[1] = (short)f2bf(lo.y);
      a[2] = (short)f2bf(lo.z); a[3] = (short)f2bf(lo.w);
      a[4] = (short)f2bf(hi.x); a[5] = (short)f2bf(hi.y);
      a[6] = (short)f2bf(hi.z); a[7] = (short)f2bf(hi.w);
      afr[ai] = a;
    }
    #pragma unroll
    for (int cf = 0; cf < 8; ++cf) {
      const int cfg = (w & 3) * 8 + cf;
      uint4 braw = BW[(kc * 32 + cfg) * 64 + l];
      bf16x8 b = __builtin_bit_cast(bf16x8, braw);
      acc[0][cf] = mfma16(afr[0], b, acc[0][cf]);
      acc[1][cf] = mfma16(afr[1], b, acc[1][cf]);
    }
  }

  #pragma unroll
  for (int ai = 0; ai < 2; ++ai) {
    #pragma unroll
    for (int cf = 0; cf < 8; ++cf) {
      const int col = colw + cf * 16 + lr;
      #pragma unroll
      for (int r = 0; r < 4; ++r) {
        const int row = rowbase + ai * 16 + g * 4 + r;
        out[(size_t)row * HID + col] = acc[ai][cf][r];
      }
    }
  }
}

// Phase 2: sequential scan. 4 blocks, each owns 16 batch rows for all 2048 steps.
// LDS (163840 B):
//   [0,      98304): B-frags kf0-2, all 32 cfgs (96 x 1KB)
//   [98304, 114688): B-frags kf3, per-wave cf0,1 ((w*2+cf)*1KB)
//   [114688,131072): h, 16 rows x 1024B, byte XOR ((row&7)<<4)
//   [131072,163840): xp, 16 rows x 2048B f32, byte XOR ((row&7)<<4)
// W_hh kf3 cf2,3 + kf4..15 in 200 VGPRs/thread (fully static indexing).
__global__ __launch_bounds__(512, 2) void rnn_scan(
    const uint4* __restrict__ BW,   // W_hh frag-major bf16 (16384 frags)
    float* __restrict__ xo) {       // d_out: xp in, h out
  extern __shared__ char smem[];
  const int tid = threadIdx.x, w = tid >> 6, l = tid & 63;
  const int g = l >> 4, lr = l & 15;
  const int bg = blockIdx.x;
  const int w4 = w * 4;

  // ---- stage LDS B-frags kf0-2 (96KB, linear = first 96 frags of BW)
  {
    uint4* lb = reinterpret_cast<uint4*>(smem);
    #pragma unroll
    for (int i = 0; i < 12; ++i) lb[i * 512 + tid] = BW[i * 512 + tid];
    // kf3 cf0,1 (16 frags) packed at 98304 as (w'*2+cf')*1KB
    #pragma unroll
    for (int i = 0; i < 2; ++i) {
      int idx = i * 512 + tid;            // 0..1023
      int fl = idx >> 6, li = idx & 63;   // fl = w'*2+cf'
      int cfg = (fl >> 1) * 4 + (fl & 1);
      reinterpret_cast<uint4*>(smem + 98304)[idx] = BW[(96 + cfg) * 64 + li];
    }
  }
  // ---- zero h
  {
    float* hz = reinterpret_cast<float*>(smem + 114688);
    #pragma unroll
    for (int i = 0; i < 8; ++i) hz[i * 512 + tid] = 0.f;
  }
  // ---- preload register B-frags (static names/indices only)
  bf16x8 br3_2 = __builtin_bit_cast(bf16x8, BW[(96 + w4 + 2) * 64 + l]);
  bf16x8 br3_3 = __builtin_bit_cast(bf16x8, BW[(96 + w4 + 3) * 64 + l]);
  bf16x8 br[12][4];
  #pragma unroll
  for (int kf = 0; kf < 12; ++kf) {
    #pragma unroll
    for (int cf = 0; cf < 4; ++cf)
      br[kf][cf] = __builtin_bit_cast(bf16x8, BW[((kf + 4) * 32 + w4 + cf) * 64 + l]);
  }
  __syncthreads();

  // ---- per-lane constants
  const int aswz  = (lr & 7) << 4;
  const int abase = 114688 + lr * 1024 + g * 16;      // + kf*64, then ^ aswz
  const int colw  = w * 64;
  const int col0  = colw + lr;
  const int g4x   = (g & 1) << 6;                      // ((g*4)&7)<<4
  const int xq    = 131072 + g * 8192 + col0 * 4;      // + r*2048 + cf*64, ^g4x^(r<<4)
  const int hw0   = 114688 + g * 4096 + col0 * 2;      // + r*1024 + cf*32, ^g4x^(r<<4)
  const int ovbase = g * 4 * HID + col0;               // + r*HID + cf*16
  int pswz[4];
  #pragma unroll
  for (int c = 0; c < 4; ++c) {
    int off = c * 8192 + tid * 16;
    pswz[c] = off ^ ((off >> 7) & 0x70);               // pre-swizzled global offset
  }

  // ---- prologue: stage xp(0) into LDS
  {
    const char* xb = (const char*)(xo + (size_t)(bg * 16) * HID);
    #pragma unroll
    for (int c = 0; c < 4; ++c)
      gld_lds16(xb + pswz[c], smem + 131072 + c * 8192 + tid * 16);
  }

  #pragma unroll 1
  for (int s = 0; s < SEQ; ++s) {
    float* xrow = xo + (size_t)(s * NBATCH + bg * 16) * HID;

    f32x4 acc[4];
    #pragma unroll
    for (int cf = 0; cf < 4; ++cf) { f32x4 z = {0.f, 0.f, 0.f, 0.f}; acc[cf] = z; }

    // ---- MFMA chain: kf0-2 (B from LDS)
    #pragma unroll
    for (int kf = 0; kf < 3; ++kf) {
      bf16x8 av = *reinterpret_cast<const bf16x8*>(smem + ((abase + kf * 64) ^ aswz));
      const char* bb = smem + ((kf * 32 + w4) << 10) + l * 16;
      acc[0] = mfma16(av, *reinterpret_cast<const bf16x8*>(bb       ), acc[0]);
      acc[1] = mfma16(av, *reinterpret_cast<const bf16x8*>(bb + 1024), acc[1]);
      acc[2] = mfma16(av, *reinterpret_cast<const bf16x8*>(bb + 2048), acc[2]);
      acc[3] = mfma16(av, *reinterpret_cast<const bf16x8*>(bb + 3072), acc[3]);
    }
    // ---- kf3 (B: cf0,1 LDS / cf2,3 regs)
    {
      bf16x8 av = *reinterpret_cast<const bf16x8*>(smem + ((abase + 3 * 64) ^ aswz));
      const char* bb = smem + 98304 + (w * 2) * 1024 + l * 16;
      acc[0] = mfma16(av, *reinterpret_cast<const bf16x8*>(bb       ), acc[0]);
      acc[1] = mfma16(av, *reinterpret_cast<const bf16x8*>(bb + 1024), acc[1]);
      acc[2] = mfma16(av, br3_2, acc[2]);
      acc[3] = mfma16(av, br3_3, acc[3]);
    }
    // ---- kf4-15 (B in regs, static indices)
    #pragma unroll
    for (int kf = 0; kf < 12; ++kf) {
      bf16x8 av = *reinterpret_cast<const bf16x8*>(smem + ((abase + (kf + 4) * 64) ^ aswz));
      acc[0] = mfma16(av, br[kf][0], acc[0]);
      acc[1] = mfma16(av, br[kf][1], acc[1]);
      acc[2] = mfma16(av, br[kf][2], acc[2]);
      acc[3] = mfma16(av, br[kf][3], acc[3]);
    }

    // ---- epilogue A: xp(s) is in LDS (glds from prev iter) -> acc += xp
    asm volatile("s_waitcnt vmcnt(0)" ::: "memory");
    #pragma unroll
    for (int cf = 0; cf < 4; ++cf) {
      #pragma unroll
      for (int r = 0; r < 4; ++r) {
        float xv = *reinterpret_cast<const float*>(
            smem + (((xq + r * 2048 + cf * 64) ^ g4x) ^ (r << 4)));
        acc[cf][r] += xv;
      }
    }
    asm volatile("s_waitcnt lgkmcnt(0)" ::: "memory");
    __builtin_amdgcn_s_barrier();          // barrier-1: all xp reads + h reads done
    __builtin_amdgcn_sched_barrier(0);

    // ---- stage xp(s+1) (lands before next epilogue's vmcnt(0))
    if (s + 1 < SEQ) {
      const char* xb = (const char*)(xo + (size_t)((s + 1) * NBATCH + bg * 16) * HID);
      #pragma unroll
      for (int c = 0; c < 4; ++c)
        gld_lds16(xb + pswz[c], smem + 131072 + c * 8192 + tid * 16);
    }

    // ---- epilogue B: tanh, store f32 out, write bf16 h to LDS
    #pragma unroll
    for (int cf = 0; cf < 4; ++cf) {
      #pragma unroll
      for (int r = 0; r < 4; ++r) {
        const float pre = acc[cf][r];
        const float hv = 1.0f - 2.0f * __builtin_amdgcn_rcpf(1.0f + __expf(2.0f * pre));
        xrow[ovbase + r * HID + cf * 16] = hv;
        const int waddr = ((hw0 + r * 1024 + cf * 32) ^ g4x) ^ (r << 4);
        *reinterpret_cast<unsigned short*>(smem + waddr) = f2bf(hv);
      }
    }
    asm volatile("s_waitcnt lgkmcnt(0)" ::: "memory");
    __builtin_amdgcn_s_barrier();          // barrier-2: h(s) ready (glds stays in flight)
    __builtin_amdgcn_sched_barrier(0);
  }
}

extern "C" void kernel_launch(void* const* d_in, const int* in_sizes, int n_in,
                              void* d_out, int out_size, void* d_ws, size_t ws_size,
                              hipStream_t stream) {
  (void)in_sizes; (void)n_in; (void)out_size;
  const float* X   = (const float*)d_in[0];
  const float* Wih = (const float*)d_in[1];
  const float* Whh = (const float*)d_in[2];
  const float* bih = (const float*)d_in[3];
  const float* bhh = (const float*)d_in[4];
  float* out = (float*)d_out;

  unsigned short* wihf = (unsigned short*)d_ws;              // 512 KB
  unsigned short* whhf = wihf + 262144;                      // 512 KB
  float* bsum = (float*)(whhf + 262144);                     // 2 KB
  if (ws_size < (size_t)(2 * 524288 + 2048)) return;

  prep_wfrag<<<1024, 256, 0, stream>>>(Wih, wihf);
  prep_wfrag<<<1024, 256, 0, stream>>>(Whh, whhf);
  prep_bsum<<<1, 512, 0, stream>>>(bih, bhh, bsum);

  rnn_xproj<<<2048, 512, 0, stream>>>(X, (const uint4*)wihf, bsum, out);

  hipFuncSetAttribute(reinterpret_cast<const void*>(rnn_scan),
                      hipFuncAttributeMaxDynamicSharedMemorySize, 163840);
  rnn_scan<<<4, 512, 163840, stream>>>((const uint4*)whhf, out);
}